// Round 2
// baseline (105.680 us; speedup 1.0000x reference)
//
#include <hip/hip_runtime.h>

constexpr int NB = 4;
constexpr int CC = 128;
constexpr int HH = 64;
constexpr int WW = 64;
constexpr int HWp = HH * WW;      // 4096
constexpr int NHEADS = 4;
constexpr int K2 = 25;

typedef unsigned int  uint32;
typedef unsigned short ushort16;

__device__ __forceinline__ ushort16 f2bf(float x) {
    uint32 b = __float_as_uint(x);
    return (ushort16)((b + 0x7FFFu + ((b >> 16) & 1u)) >> 16);   // RNE
}
__device__ __forceinline__ uint32 pack2(float lo, float hi) {
    return ((uint32)f2bf(hi) << 16) | (uint32)f2bf(lo);
}
__device__ __forceinline__ float bf_lo(uint32 u) { return __uint_as_float(u << 16); }
__device__ __forceinline__ float bf_hi(uint32 u) { return __uint_as_float(u & 0xFFFF0000u); }

// ---------------------------------------------------------------------------
// Kernel 1: projections q/k/v -> qp/kp/vp (bf16), CHW fp32 input -> HWC bf16.
// grid = 3 * NB * (HW/128) = 384 blocks, 256 threads.
// ---------------------------------------------------------------------------
__global__ __launch_bounds__(256) void proj_kernel(
    const float* __restrict__ q, const float* __restrict__ k, const float* __restrict__ v,
    const float* __restrict__ Wq, const float* __restrict__ Wk, const float* __restrict__ Wv,
    ushort16* __restrict__ qp, ushort16* __restrict__ kp, ushort16* __restrict__ vp)
{
    __shared__ float lw[128 * 132];   // W transposed: lw[c*132 + o]

    int blk  = blockIdx.x;
    int p    = blk % 3;
    int tile = blk / 3;
    int n    = tile >> 5;
    int pt   = tile & 31;

    const float* Wsel = (p == 0) ? Wq : ((p == 1) ? Wk : Wv);
    const float* isel = (p == 0) ? q  : ((p == 1) ? k  : v);
    ushort16*    osel = (p == 0) ? qp : ((p == 1) ? kp : vp);

    for (int i = threadIdx.x; i < 128 * 128; i += 256) {
        int o = i >> 7, c = i & 127;
        lw[c * 132 + o] = Wsel[i];
    }
    __syncthreads();

    int l  = threadIdx.x & 63;
    int og = threadIdx.x >> 6;        // 0..3 -> 32-channel output chunk
    int pix0 = pt * 128;
    const float* in0 = isel + (size_t)n * CC * HWp + pix0 + l;

    float acc0[32], acc1[32];
#pragma unroll
    for (int i = 0; i < 32; ++i) { acc0[i] = 0.f; acc1[i] = 0.f; }

    for (int c = 0; c < 128; ++c) {
        float a = in0[c * HWp];
        float b = in0[c * HWp + 64];
        const float4* wr = reinterpret_cast<const float4*>(&lw[c * 132 + og * 32]);
#pragma unroll
        for (int i4 = 0; i4 < 8; ++i4) {
            float4 wv = wr[i4];
            acc0[i4*4+0] = fmaf(wv.x, a, acc0[i4*4+0]);
            acc0[i4*4+1] = fmaf(wv.y, a, acc0[i4*4+1]);
            acc0[i4*4+2] = fmaf(wv.z, a, acc0[i4*4+2]);
            acc0[i4*4+3] = fmaf(wv.w, a, acc0[i4*4+3]);
            acc1[i4*4+0] = fmaf(wv.x, b, acc1[i4*4+0]);
            acc1[i4*4+1] = fmaf(wv.y, b, acc1[i4*4+1]);
            acc1[i4*4+2] = fmaf(wv.z, b, acc1[i4*4+2]);
            acc1[i4*4+3] = fmaf(wv.w, b, acc1[i4*4+3]);
        }
    }

    ushort16* o0 = osel + ((size_t)(n * HWp + pix0 + l)) * CC + og * 32;
    ushort16* o1 = o0 + 64 * CC;
#pragma unroll
    for (int g = 0; g < 4; ++g) {
        uint4 w0 = make_uint4(pack2(acc0[g*8+0], acc0[g*8+1]), pack2(acc0[g*8+2], acc0[g*8+3]),
                              pack2(acc0[g*8+4], acc0[g*8+5]), pack2(acc0[g*8+6], acc0[g*8+7]));
        reinterpret_cast<uint4*>(o0)[g] = w0;
        uint4 w1 = make_uint4(pack2(acc1[g*8+0], acc1[g*8+1]), pack2(acc1[g*8+2], acc1[g*8+3]),
                              pack2(acc1[g*8+4], acc1[g*8+5]), pack2(acc1[g*8+6], acc1[g*8+7]));
        reinterpret_cast<uint4*>(o1)[g] = w1;
    }
}

// ---------------------------------------------------------------------------
// Kernel 2: fused flow sampling + multi-head attention.
// grid = NB*HW blocks (one pixel), 64 threads (2 channels/thread, 1 wave).
// All 25 taps share one fractional offset -> one 6x6 patch per channel.
// oh is written IN-PLACE into the qp slab (each thread reads its own qp
// element first, writes same address last; no cross-block qp reads).
// ---------------------------------------------------------------------------
__global__ __launch_bounds__(64) void attn_kernel(
    ushort16* qoh,                           // qp in, oh out (same slab, aliased)
    const ushort16* __restrict__ kp, const ushort16* __restrict__ vp,
    const float* __restrict__ flow,
    float* __restrict__ attn)                // [N][NHEADS][K2][HW]
{
    int blk = blockIdx.x;
    int swz = ((blk & 7) << 11) + (blk >> 3);   // XCD-contiguous pixel bands
    int n   = swz >> 12;
    int yx  = swz & 4095;
    int y   = yx >> 6;
    int x   = yx & 63;
    int tid = threadIdx.x;                   // 0..63
    int c0  = tid * 2;
    int lih = tid & 15;                      // lane within 16-lane head group

    float fx = flow[((size_t)n * 2 + 0) * HWp + yx];
    float fy = flow[((size_t)n * 2 + 1) * HWp + yx];
    float px = (float)x + fx;
    float py = (float)y + fy;
    float X0 = floorf(px), Y0 = floorf(py);
    float wx = px - X0,    wy = py - Y0;
    int ix0 = (int)X0 - 2, iy0 = (int)Y0 - 2;

    int   coff[6], roff[6];
    float mx[6], my[6];
#pragma unroll
    for (int r = 0; r < 6; ++r) {
        int xi = ix0 + r;
        mx[r] = (xi >= 0 && xi < WW) ? 1.f : 0.f;
        int xc = xi < 0 ? 0 : (xi > WW - 1 ? WW - 1 : xi);
        coff[r] = xc * CC;
        int yi = iy0 + r;
        my[r] = (yi >= 0 && yi < HH) ? 1.f : 0.f;
        int yc = yi < 0 ? 0 : (yi > HH - 1 ? HH - 1 : yi);
        roff[r] = yc * WW * CC;
    }

    const ushort16* kb = kp + (size_t)n * HWp * CC + c0;
    const ushort16* vb = vp + (size_t)n * HWp * CC + c0;
    ushort16* qb = qoh + ((size_t)(n * HWp + yx)) * CC + c0;

    uint32 qpk = *reinterpret_cast<const uint32*>(qb);
    float q0 = bf_lo(qpk), q1 = bf_hi(qpk);

    // ---- pass 1: K patch -> per-position 2ch dot -> blends -> logits ----
    float hb[30];
#pragma unroll
    for (int r = 0; r < 6; ++r) {
        float pd[6];
#pragma unroll
        for (int rx = 0; rx < 6; ++rx) {
            uint32 u = *reinterpret_cast<const uint32*>(kb + roff[r] + coff[rx]);
            pd[rx] = (q0 * bf_lo(u) + q1 * bf_hi(u)) * (my[r] * mx[rx]);
        }
#pragma unroll
        for (int kx = 0; kx < 5; ++kx)
            hb[r * 5 + kx] = pd[kx] * (1.f - wx) + pd[kx + 1] * wx;
    }

    float l[25];
#pragma unroll
    for (int ky = 0; ky < 5; ++ky)
#pragma unroll
        for (int kx = 0; kx < 5; ++kx)
            l[ky * 5 + kx] = (1.f - wy) * hb[ky * 5 + kx] + wy * hb[(ky + 1) * 5 + kx];

    // reduce over 16 lanes (= 32 channels) of this head
#pragma unroll
    for (int kk = 0; kk < 25; ++kk) {
        float s = l[kk];
        s += __shfl_xor(s, 1);
        s += __shfl_xor(s, 2);
        s += __shfl_xor(s, 4);
        s += __shfl_xor(s, 8);
        l[kk] = s * 0.17677669529663687f;    // 1/sqrt(32)
    }

    // ---- softmax over 25 (replicated in all lanes of the head) ----
    float m = l[0];
#pragma unroll
    for (int kk = 1; kk < 25; ++kk) m = fmaxf(m, l[kk]);
    float sum = 0.f;
#pragma unroll
    for (int kk = 0; kk < 25; ++kk) { l[kk] = __expf(l[kk] - m); sum += l[kk]; }
    float inv = 1.f / sum;
#pragma unroll
    for (int kk = 0; kk < 25; ++kk) l[kk] *= inv;

    // attn output: head = tid>>4; lane lih writes kk = lih and lih+16
    {
        int head = tid >> 4;
        float* ab = attn + (((size_t)n * NHEADS + head) * K2) * HWp + yx;
        ab[lih * HWp] = l[lih < 25 ? lih : 0];        // lih in 0..15, all < 25
        if (lih < 9) ab[(lih + 16) * HWp] = l[lih + 16];
    }

    // ---- fold softmax + bilinear + border mask into 6x6 weights ----
    float t[30];
#pragma unroll
    for (int ky = 0; ky < 5; ++ky)
#pragma unroll
        for (int rx = 0; rx < 6; ++rx) {
            float s = 0.f;
            if (rx < 5)  s += l[ky * 5 + rx] * (1.f - wx);
            if (rx >= 1) s += l[ky * 5 + rx - 1] * wx;
            t[ky * 6 + rx] = s;
        }
    float w6[36];
#pragma unroll
    for (int ry = 0; ry < 6; ++ry)
#pragma unroll
        for (int rx = 0; rx < 6; ++rx) {
            float s = 0.f;
            if (ry < 5)  s += t[ry * 6 + rx] * (1.f - wy);
            if (ry >= 1) s += t[(ry - 1) * 6 + rx] * wy;
            w6[ry * 6 + rx] = s * (my[ry] * mx[rx]);
        }

    // ---- pass 2: V patch weighted sum (2 channels) ----
    float a0 = 0.f, a1 = 0.f;
#pragma unroll
    for (int r = 0; r < 6; ++r)
#pragma unroll
        for (int rx = 0; rx < 6; ++rx) {
            uint32 u = *reinterpret_cast<const uint32*>(vb + roff[r] + coff[rx]);
            float w = w6[r * 6 + rx];
            a0 = fmaf(bf_lo(u), w, a0);
            a1 = fmaf(bf_hi(u), w, a1);
        }

    *reinterpret_cast<uint32*>(qb) = pack2(a0, a1);   // oh, in-place over qp
}

// ---------------------------------------------------------------------------
// Kernel 3: final projection, HWC bf16 input -> CHW fp32 output.
// grid = NB*(HW/64) = 256 blocks, 256 threads.
// ---------------------------------------------------------------------------
__global__ __launch_bounds__(256) void fc_kernel(
    const ushort16* __restrict__ outh, const float* __restrict__ Wfc,
    float* __restrict__ out)
{
    __shared__ float lw[128 * 132];   // Wfc^T
    __shared__ float li[64 * 129];    // input tile [pix][c]

    int blk  = blockIdx.x;
    int n    = blk >> 6;
    int pt   = blk & 63;
    int pix0 = pt * 64;

    for (int i = threadIdx.x; i < 128 * 128; i += 256) {
        int o = i >> 7, c = i & 127;
        lw[c * 132 + o] = Wfc[i];
    }
    const uint32* ib = reinterpret_cast<const uint32*>(outh + (size_t)(n * HWp + pix0) * CC);
    for (int i = threadIdx.x; i < 64 * 64; i += 256) {
        int pix = i >> 6, cu = i & 63;
        uint32 u = ib[pix * 64 + cu];
        li[pix * 129 + cu * 2]     = bf_lo(u);
        li[pix * 129 + cu * 2 + 1] = bf_hi(u);
    }
    __syncthreads();

    int l  = threadIdx.x & 63;
    int og = threadIdx.x >> 6;
    float acc[32];
#pragma unroll
    for (int i = 0; i < 32; ++i) acc[i] = 0.f;

    for (int c = 0; c < 128; ++c) {
        float a = li[l * 129 + c];
        const float4* wr = reinterpret_cast<const float4*>(&lw[c * 132 + og * 32]);
#pragma unroll
        for (int i4 = 0; i4 < 8; ++i4) {
            float4 wv = wr[i4];
            acc[i4*4+0] = fmaf(wv.x, a, acc[i4*4+0]);
            acc[i4*4+1] = fmaf(wv.y, a, acc[i4*4+1]);
            acc[i4*4+2] = fmaf(wv.z, a, acc[i4*4+2]);
            acc[i4*4+3] = fmaf(wv.w, a, acc[i4*4+3]);
        }
    }

    float* ob = out + (size_t)n * CC * HWp + pix0 + l;
#pragma unroll
    for (int i = 0; i < 32; ++i)
        ob[(og * 32 + i) * HWp] = acc[i];
}

// ---------------------------------------------------------------------------
extern "C" void kernel_launch(void* const* d_in, const int* in_sizes, int n_in,
                              void* d_out, int out_size, void* d_ws, size_t ws_size,
                              hipStream_t stream)
{
    const float* q    = (const float*)d_in[0];
    const float* k    = (const float*)d_in[1];
    const float* v    = (const float*)d_in[2];
    const float* flow = (const float*)d_in[3];
    const float* Wq   = (const float*)d_in[4];
    const float* Wk   = (const float*)d_in[5];
    const float* Wv   = (const float*)d_in[6];
    const float* Wfc  = (const float*)d_in[7];

    float* out  = (float*)d_out;                          // [N][C][H][W]
    float* attn = out + (size_t)NB * CC * HWp;            // [N][NHEADS][K2][H][W]

    // workspace: 3 bf16 slabs of NB*HW*C = 4 MB each -> 12 MB total
    ushort16* ws = (ushort16*)d_ws;
    size_t slab = (size_t)NB * HWp * CC;                  // 2,097,152 elements
    ushort16* qp = ws;                                    // later reused as oh
    ushort16* kp = ws + slab;
    ushort16* vp = ws + 2 * slab;

    proj_kernel<<<dim3(3 * NB * (HWp / 128)), dim3(256), 0, stream>>>(
        q, k, v, Wq, Wk, Wv, qp, kp, vp);
    attn_kernel<<<dim3(NB * HWp), dim3(64), 0, stream>>>(
        qp, kp, vp, flow, attn);
    fc_kernel<<<dim3(NB * (HWp / 64)), dim3(256), 0, stream>>>(
        qp, Wfc, out);
}

// Round 3
// 69.517 us; speedup vs baseline: 1.5202x; 1.5202x over previous
//
#include <hip/hip_runtime.h>

constexpr int NB = 4;
constexpr int CC = 128;
constexpr int HH = 64;
constexpr int WW = 64;
constexpr int HWp = HH * WW;      // 4096
constexpr int NHEADS = 4;
constexpr int K2 = 25;

typedef unsigned int   uint32;
typedef unsigned short ushort16;
typedef __attribute__((ext_vector_type(8))) short bf16x8;
typedef __attribute__((ext_vector_type(4))) float f32x4;

__device__ __forceinline__ ushort16 f2bf(float x) {
    uint32 b = __float_as_uint(x);
    return (ushort16)((b + 0x7FFFu + ((b >> 16) & 1u)) >> 16);   // RNE
}
__device__ __forceinline__ uint32 pack2(float lo, float hi) {
    return ((uint32)f2bf(hi) << 16) | (uint32)f2bf(lo);
}
__device__ __forceinline__ float bf_lo(uint32 u) { return __uint_as_float(u << 16); }
__device__ __forceinline__ float bf_hi(uint32 u) { return __uint_as_float(u & 0xFFFF0000u); }

// ---------------------------------------------------------------------------
// Kernel 0: convert Wq/Wk/Wv/Wfc fp32 -> bf16 (row-major preserved).
// grid = 64 blocks x 256 threads; thread converts 4 elements.
// ---------------------------------------------------------------------------
__global__ __launch_bounds__(256) void wconv_kernel(
    const float* __restrict__ Wq, const float* __restrict__ Wk,
    const float* __restrict__ Wv, const float* __restrict__ Wfc,
    ushort16* __restrict__ wbf)
{
    int i = blockIdx.x * 256 + threadIdx.x;   // 0..16383
    int m = i >> 12;                          // matrix id (uniform per block)
    int j = i & 4095;                         // float4 index within matrix
    const float* s = (m == 0) ? Wq : ((m == 1) ? Wk : ((m == 2) ? Wv : Wfc));
    float4 f = reinterpret_cast<const float4*>(s)[j];
    uint32 w0 = pack2(f.x, f.y);
    uint32 w1 = pack2(f.z, f.w);
    uint32* d = reinterpret_cast<uint32*>(wbf + (size_t)m * 16384);
    d[j * 2]     = w0;
    d[j * 2 + 1] = w1;
}

// ---------------------------------------------------------------------------
// Kernel 1: MFMA projections. C[out=128][pix] = W[128x128] * X[c=128][pix].
// grid = 3 * NB * 64 = 768 blocks, 256 threads (4 waves, 2x2 wave grid).
// Block tile: 128 out x 64 pix. X staged to LDS as bf16 [pix][c] (stride 132).
// Output HWC bf16.
// ---------------------------------------------------------------------------
__global__ __launch_bounds__(256) void proj_mfma(
    const float* __restrict__ q, const float* __restrict__ k, const float* __restrict__ v,
    const ushort16* __restrict__ wbf,
    ushort16* __restrict__ qp, ushort16* __restrict__ kp, ushort16* __restrict__ vp)
{
    __shared__ __align__(16) ushort16 lx[64 * 132];

    int blk = blockIdx.x;
    int p   = blk >> 8;               // 0..2 (256 blocks per projection)
    int rem = blk & 255;
    int n   = rem >> 6;
    int pt  = rem & 63;
    int pix0 = pt * 64;

    const float*    X  = (p == 0) ? q  : ((p == 1) ? k  : v);
    ushort16*       O  = (p == 0) ? qp : ((p == 1) ? kp : vp);
    const ushort16* Wb = wbf + (size_t)p * 16384;
    const float*    Xb = X + (size_t)n * CC * HWp + pix0;

    int lane = threadIdx.x & 63;
    int cg   = threadIdx.x >> 6;

    // stage + transpose + cvt: X fp32 [c][pix] -> LDS bf16 [pix][c]
#pragma unroll
    for (int i = 0; i < 16; ++i) {
        int c0 = i * 8 + cg * 2;
        float a = Xb[c0 * HWp + lane];
        float b = Xb[(c0 + 1) * HWp + lane];
        *reinterpret_cast<uint32*>(&lx[lane * 132 + c0]) = pack2(a, b);
    }
    __syncthreads();

    int wid = threadIdx.x >> 6;
    int wr  = wid >> 1, wc = wid & 1;   // wave tile: out 64 x pix 32
    int p16 = lane & 15, kg = lane >> 4;

    f32x4 acc[4][2] = {};

#pragma unroll
    for (int k0 = 0; k0 < 128; k0 += 32) {
        bf16x8 A[4], B[2];
#pragma unroll
        for (int ai = 0; ai < 4; ++ai) {
            int o = wr * 64 + ai * 16 + p16;
            A[ai] = *reinterpret_cast<const bf16x8*>(&Wb[o * 128 + k0 + kg * 8]);
        }
#pragma unroll
        for (int bj = 0; bj < 2; ++bj) {
            int px = wc * 32 + bj * 16 + p16;
            const ushort16* sp = &lx[px * 132 + k0 + kg * 8];
            struct { unsigned long long lo, hi; } t;
            t.lo = *reinterpret_cast<const unsigned long long*>(sp);
            t.hi = *reinterpret_cast<const unsigned long long*>(sp + 4);
            B[bj] = __builtin_bit_cast(bf16x8, t);
        }
#pragma unroll
        for (int ai = 0; ai < 4; ++ai)
#pragma unroll
            for (int bj = 0; bj < 2; ++bj)
                acc[ai][bj] = __builtin_amdgcn_mfma_f32_16x16x32_bf16(
                    A[ai], B[bj], acc[ai][bj], 0, 0, 0);
    }

    // epilogue: D col=lane&15 -> pix, row=(lane>>4)*4+r -> out. HWC bf16.
    ushort16* Ob = O + (size_t)(n * HWp + pix0) * CC;
#pragma unroll
    for (int ai = 0; ai < 4; ++ai) {
        int ob = wr * 64 + ai * 16 + kg * 4;
#pragma unroll
        for (int bj = 0; bj < 2; ++bj) {
            int px = wc * 32 + bj * 16 + p16;
            uint32* dst = reinterpret_cast<uint32*>(&Ob[(size_t)px * CC + ob]);
            dst[0] = pack2(acc[ai][bj][0], acc[ai][bj][1]);
            dst[1] = pack2(acc[ai][bj][2], acc[ai][bj][3]);
        }
    }
}

// ---------------------------------------------------------------------------
// Kernel 2: fused flow sampling + multi-head attention (unchanged).
// grid = NB*HW blocks (one pixel), 64 threads (2 channels/thread, 1 wave).
// oh written IN-PLACE into the qp slab.
// ---------------------------------------------------------------------------
__global__ __launch_bounds__(64) void attn_kernel(
    ushort16* qoh,
    const ushort16* __restrict__ kp, const ushort16* __restrict__ vp,
    const float* __restrict__ flow,
    float* __restrict__ attn)
{
    int blk = blockIdx.x;
    int swz = ((blk & 7) << 11) + (blk >> 3);
    int n   = swz >> 12;
    int yx  = swz & 4095;
    int y   = yx >> 6;
    int x   = yx & 63;
    int tid = threadIdx.x;
    int c0  = tid * 2;
    int lih = tid & 15;

    float fx = flow[((size_t)n * 2 + 0) * HWp + yx];
    float fy = flow[((size_t)n * 2 + 1) * HWp + yx];
    float px = (float)x + fx;
    float py = (float)y + fy;
    float X0 = floorf(px), Y0 = floorf(py);
    float wx = px - X0,    wy = py - Y0;
    int ix0 = (int)X0 - 2, iy0 = (int)Y0 - 2;

    int   coff[6], roff[6];
    float mx[6], my[6];
#pragma unroll
    for (int r = 0; r < 6; ++r) {
        int xi = ix0 + r;
        mx[r] = (xi >= 0 && xi < WW) ? 1.f : 0.f;
        int xc = xi < 0 ? 0 : (xi > WW - 1 ? WW - 1 : xi);
        coff[r] = xc * CC;
        int yi = iy0 + r;
        my[r] = (yi >= 0 && yi < HH) ? 1.f : 0.f;
        int yc = yi < 0 ? 0 : (yi > HH - 1 ? HH - 1 : yi);
        roff[r] = yc * WW * CC;
    }

    const ushort16* kb = kp + (size_t)n * HWp * CC + c0;
    const ushort16* vb = vp + (size_t)n * HWp * CC + c0;
    ushort16* qb = qoh + ((size_t)(n * HWp + yx)) * CC + c0;

    uint32 qpk = *reinterpret_cast<const uint32*>(qb);
    float q0 = bf_lo(qpk), q1 = bf_hi(qpk);

    float hb[30];
#pragma unroll
    for (int r = 0; r < 6; ++r) {
        float pd[6];
#pragma unroll
        for (int rx = 0; rx < 6; ++rx) {
            uint32 u = *reinterpret_cast<const uint32*>(kb + roff[r] + coff[rx]);
            pd[rx] = (q0 * bf_lo(u) + q1 * bf_hi(u)) * (my[r] * mx[rx]);
        }
#pragma unroll
        for (int kx = 0; kx < 5; ++kx)
            hb[r * 5 + kx] = pd[kx] * (1.f - wx) + pd[kx + 1] * wx;
    }

    float l[25];
#pragma unroll
    for (int ky = 0; ky < 5; ++ky)
#pragma unroll
        for (int kx = 0; kx < 5; ++kx)
            l[ky * 5 + kx] = (1.f - wy) * hb[ky * 5 + kx] + wy * hb[(ky + 1) * 5 + kx];

#pragma unroll
    for (int kk = 0; kk < 25; ++kk) {
        float s = l[kk];
        s += __shfl_xor(s, 1);
        s += __shfl_xor(s, 2);
        s += __shfl_xor(s, 4);
        s += __shfl_xor(s, 8);
        l[kk] = s * 0.17677669529663687f;
    }

    float m = l[0];
#pragma unroll
    for (int kk = 1; kk < 25; ++kk) m = fmaxf(m, l[kk]);
    float sum = 0.f;
#pragma unroll
    for (int kk = 0; kk < 25; ++kk) { l[kk] = __expf(l[kk] - m); sum += l[kk]; }
    float inv = 1.f / sum;
#pragma unroll
    for (int kk = 0; kk < 25; ++kk) l[kk] *= inv;

    {
        int head = tid >> 4;
        float* ab = attn + (((size_t)n * NHEADS + head) * K2) * HWp + yx;
        ab[lih * HWp] = l[lih < 25 ? lih : 0];
        if (lih < 9) ab[(lih + 16) * HWp] = l[lih + 16];
    }

    float t[30];
#pragma unroll
    for (int ky = 0; ky < 5; ++ky)
#pragma unroll
        for (int rx = 0; rx < 6; ++rx) {
            float s = 0.f;
            if (rx < 5)  s += l[ky * 5 + rx] * (1.f - wx);
            if (rx >= 1) s += l[ky * 5 + rx - 1] * wx;
            t[ky * 6 + rx] = s;
        }
    float w6[36];
#pragma unroll
    for (int ry = 0; ry < 6; ++ry)
#pragma unroll
        for (int rx = 0; rx < 6; ++rx) {
            float s = 0.f;
            if (ry < 5)  s += t[ry * 6 + rx] * (1.f - wy);
            if (ry >= 1) s += t[(ry - 1) * 6 + rx] * wy;
            w6[ry * 6 + rx] = s * (my[ry] * mx[rx]);
        }

    float a0 = 0.f, a1 = 0.f;
#pragma unroll
    for (int r = 0; r < 6; ++r)
#pragma unroll
        for (int rx = 0; rx < 6; ++rx) {
            uint32 u = *reinterpret_cast<const uint32*>(vb + roff[r] + coff[rx]);
            float w = w6[r * 6 + rx];
            a0 = fmaf(bf_lo(u), w, a0);
            a1 = fmaf(bf_hi(u), w, a1);
        }

    *reinterpret_cast<uint32*>(qb) = pack2(a0, a1);
}

// ---------------------------------------------------------------------------
// Kernel 3: MFMA final projection. out[o][pix] = Wfc[128x128] * oh[pix][c]^T.
// grid = 16384/64 = 256 blocks, 256 threads. No LDS: B direct from bf16 HWC.
// ---------------------------------------------------------------------------
__global__ __launch_bounds__(256) void fc_mfma(
    const ushort16* __restrict__ oh, const ushort16* __restrict__ wfcb,
    float* __restrict__ out)
{
    int blk = blockIdx.x;
    int gp0 = blk * 64;               // global pixel base
    int n   = gp0 >> 12;
    int yx0 = gp0 & 4095;

    int lane = threadIdx.x & 63;
    int wid  = threadIdx.x >> 6;
    int wr = wid >> 1, wc = wid & 1;
    int p16 = lane & 15, kg = lane >> 4;

    const ushort16* ohb = oh + (size_t)gp0 * CC;

    f32x4 acc[4][2] = {};

#pragma unroll
    for (int k0 = 0; k0 < 128; k0 += 32) {
        bf16x8 A[4], B[2];
#pragma unroll
        for (int ai = 0; ai < 4; ++ai) {
            int o = wr * 64 + ai * 16 + p16;
            A[ai] = *reinterpret_cast<const bf16x8*>(&wfcb[o * 128 + k0 + kg * 8]);
        }
#pragma unroll
        for (int bj = 0; bj < 2; ++bj) {
            int px = wc * 32 + bj * 16 + p16;
            B[bj] = *reinterpret_cast<const bf16x8*>(&ohb[(size_t)px * CC + k0 + kg * 8]);
        }
#pragma unroll
        for (int ai = 0; ai < 4; ++ai)
#pragma unroll
            for (int bj = 0; bj < 2; ++bj)
                acc[ai][bj] = __builtin_amdgcn_mfma_f32_16x16x32_bf16(
                    A[ai], B[bj], acc[ai][bj], 0, 0, 0);
    }

    float* ob = out + (size_t)n * CC * HWp + yx0;
#pragma unroll
    for (int ai = 0; ai < 4; ++ai) {
        int o = wr * 64 + ai * 16 + kg * 4;
#pragma unroll
        for (int bj = 0; bj < 2; ++bj) {
            int px = wc * 32 + bj * 16 + p16;
#pragma unroll
            for (int r = 0; r < 4; ++r)
                ob[(size_t)(o + r) * HWp + px] = acc[ai][bj][r];
        }
    }
}

// ---------------------------------------------------------------------------
extern "C" void kernel_launch(void* const* d_in, const int* in_sizes, int n_in,
                              void* d_out, int out_size, void* d_ws, size_t ws_size,
                              hipStream_t stream)
{
    const float* q    = (const float*)d_in[0];
    const float* k    = (const float*)d_in[1];
    const float* v    = (const float*)d_in[2];
    const float* flow = (const float*)d_in[3];
    const float* Wq   = (const float*)d_in[4];
    const float* Wk   = (const float*)d_in[5];
    const float* Wv   = (const float*)d_in[6];
    const float* Wfc  = (const float*)d_in[7];

    float* out  = (float*)d_out;                          // [N][C][H][W]
    float* attn = out + (size_t)NB * CC * HWp;            // [N][NHEADS][K2][H][W]

    // workspace: qp/kp/vp bf16 slabs (4 MB each) + Wbf16 (128 KB) = 12.13 MB
    ushort16* ws = (ushort16*)d_ws;
    size_t slab = (size_t)NB * HWp * CC;                  // 2,097,152 elements
    ushort16* qp  = ws;                                   // reused as oh
    ushort16* kp  = ws + slab;
    ushort16* vp  = ws + 2 * slab;
    ushort16* wbf = ws + 3 * slab;                        // 4 x 16384 bf16

    wconv_kernel<<<dim3(64), dim3(256), 0, stream>>>(Wq, Wk, Wv, Wfc, wbf);
    proj_mfma<<<dim3(768), dim3(256), 0, stream>>>(q, k, v, wbf, qp, kp, vp);
    attn_kernel<<<dim3(NB * HWp), dim3(64), 0, stream>>>(qp, kp, vp, flow, attn);
    fc_mfma<<<dim3(256), dim3(256), 0, stream>>>(qp, wbf + 3 * 16384, out);
}

// Round 4
// 49.601 us; speedup vs baseline: 2.1306x; 1.4015x over previous
//
#include <hip/hip_runtime.h>

constexpr int NB = 4;
constexpr int CC = 128;
constexpr int HH = 64;
constexpr int WW = 64;
constexpr int HWp = HH * WW;      // 4096
constexpr int NHEADS = 4;
constexpr int K2 = 25;

typedef unsigned int   uint32;
typedef unsigned short ushort16;
typedef __attribute__((ext_vector_type(8))) short bf16x8;
typedef __attribute__((ext_vector_type(4))) float f32x4;

__device__ __forceinline__ ushort16 f2bf(float x) {
    uint32 b = __float_as_uint(x);
    return (ushort16)((b + 0x7FFFu + ((b >> 16) & 1u)) >> 16);   // RNE
}
__device__ __forceinline__ uint32 pack2(float lo, float hi) {
    return ((uint32)f2bf(hi) << 16) | (uint32)f2bf(lo);
}
__device__ __forceinline__ float bf_lo(uint32 u) { return __uint_as_float(u << 16); }
__device__ __forceinline__ float bf_hi(uint32 u) { return __uint_as_float(u & 0xFFFF0000u); }

// ---------------------------------------------------------------------------
// Kernel 0: convert Wq/Wk/Wv/Wfc fp32 -> bf16 (row-major preserved).
// ---------------------------------------------------------------------------
__global__ __launch_bounds__(256) void wconv_kernel(
    const float* __restrict__ Wq, const float* __restrict__ Wk,
    const float* __restrict__ Wv, const float* __restrict__ Wfc,
    ushort16* __restrict__ wbf)
{
    int i = blockIdx.x * 256 + threadIdx.x;   // 0..16383
    int m = i >> 12;
    int j = i & 4095;
    const float* s = (m == 0) ? Wq : ((m == 1) ? Wk : ((m == 2) ? Wv : Wfc));
    float4 f = reinterpret_cast<const float4*>(s)[j];
    uint32 w0 = pack2(f.x, f.y);
    uint32 w1 = pack2(f.z, f.w);
    uint32* d = reinterpret_cast<uint32*>(wbf + (size_t)m * 16384);
    d[j * 2]     = w0;
    d[j * 2 + 1] = w1;
}

// ---------------------------------------------------------------------------
// Kernel 1: MFMA projections. C[out=128][pix] = W[128x128] * X[c=128][pix].
// grid = 3 * NB * 64 = 768 blocks, 256 threads (2x2 wave grid).
// ---------------------------------------------------------------------------
__global__ __launch_bounds__(256) void proj_mfma(
    const float* __restrict__ q, const float* __restrict__ k, const float* __restrict__ v,
    const ushort16* __restrict__ wbf,
    ushort16* __restrict__ qp, ushort16* __restrict__ kp, ushort16* __restrict__ vp)
{
    __shared__ __align__(16) ushort16 lx[64 * 132];

    int blk = blockIdx.x;
    int p   = blk >> 8;
    int rem = blk & 255;
    int n   = rem >> 6;
    int pt  = rem & 63;
    int pix0 = pt * 64;

    const float*    X  = (p == 0) ? q  : ((p == 1) ? k  : v);
    ushort16*       O  = (p == 0) ? qp : ((p == 1) ? kp : vp);
    const ushort16* Wb = wbf + (size_t)p * 16384;
    const float*    Xb = X + (size_t)n * CC * HWp + pix0;

    int lane = threadIdx.x & 63;
    int cg   = threadIdx.x >> 6;

#pragma unroll
    for (int i = 0; i < 16; ++i) {
        int c0 = i * 8 + cg * 2;
        float a = Xb[c0 * HWp + lane];
        float b = Xb[(c0 + 1) * HWp + lane];
        *reinterpret_cast<uint32*>(&lx[lane * 132 + c0]) = pack2(a, b);
    }
    __syncthreads();

    int wid = threadIdx.x >> 6;
    int wr  = wid >> 1, wc = wid & 1;
    int p16 = lane & 15, kg = lane >> 4;

    f32x4 acc[4][2] = {};

#pragma unroll
    for (int k0 = 0; k0 < 128; k0 += 32) {
        bf16x8 A[4], B[2];
#pragma unroll
        for (int ai = 0; ai < 4; ++ai) {
            int o = wr * 64 + ai * 16 + p16;
            A[ai] = *reinterpret_cast<const bf16x8*>(&Wb[o * 128 + k0 + kg * 8]);
        }
#pragma unroll
        for (int bj = 0; bj < 2; ++bj) {
            int px = wc * 32 + bj * 16 + p16;
            const ushort16* sp = &lx[px * 132 + k0 + kg * 8];
            struct { unsigned long long lo, hi; } t;
            t.lo = *reinterpret_cast<const unsigned long long*>(sp);
            t.hi = *reinterpret_cast<const unsigned long long*>(sp + 4);
            B[bj] = __builtin_bit_cast(bf16x8, t);
        }
#pragma unroll
        for (int ai = 0; ai < 4; ++ai)
#pragma unroll
            for (int bj = 0; bj < 2; ++bj)
                acc[ai][bj] = __builtin_amdgcn_mfma_f32_16x16x32_bf16(
                    A[ai], B[bj], acc[ai][bj], 0, 0, 0);
    }

    ushort16* Ob = O + (size_t)(n * HWp + pix0) * CC;
#pragma unroll
    for (int ai = 0; ai < 4; ++ai) {
        int ob = wr * 64 + ai * 16 + kg * 4;
#pragma unroll
        for (int bj = 0; bj < 2; ++bj) {
            int px = wc * 32 + bj * 16 + p16;
            uint32* dst = reinterpret_cast<uint32*>(&Ob[(size_t)px * CC + ob]);
            dst[0] = pack2(acc[ai][bj][0], acc[ai][bj][1]);
            dst[1] = pack2(acc[ai][bj][2], acc[ai][bj][3]);
        }
    }
}

// ---------------------------------------------------------------------------
// Kernel 2: fused flow sampling + multi-head attention.
// 256 threads = 4 waves; 16 lanes per pixel (8 ch/lane), 16 pixels per block.
// grid = 1024. oh written IN-PLACE into the qp slab.
// ---------------------------------------------------------------------------
__global__ __launch_bounds__(256) void attn_kernel(
    ushort16* qoh,
    const ushort16* __restrict__ kp, const ushort16* __restrict__ vp,
    const float* __restrict__ flow,
    float* __restrict__ attn)
{
    int blk = blockIdx.x;                        // 0..1023
    int swz = ((blk & 7) << 7) + (blk >> 3);     // XCD-contiguous bands
    int tid = threadIdx.x;
    int pix = swz * 16 + (tid >> 4);             // global pixel 0..16383
    int lg  = tid & 15;                          // lane within pixel group
    int c0  = lg * 8;
    int n   = pix >> 12;
    int yx  = pix & 4095;
    int y   = yx >> 6, x = yx & 63;

    float fx = flow[((size_t)n * 2 + 0) * HWp + yx];
    float fy = flow[((size_t)n * 2 + 1) * HWp + yx];
    float pxf = (float)x + fx, pyf = (float)y + fy;
    float X0 = floorf(pxf), Y0 = floorf(pyf);
    float wx = pxf - X0,    wy = pyf - Y0;
    int ix0 = (int)X0 - 2,  iy0 = (int)Y0 - 2;

    int coff[6], roff[6];
    float mx[6], my[6];
#pragma unroll
    for (int r = 0; r < 6; ++r) {
        int xi = ix0 + r;
        mx[r] = (xi >= 0 && xi < WW) ? 1.f : 0.f;
        int xc = xi < 0 ? 0 : (xi > WW - 1 ? WW - 1 : xi);
        coff[r] = xc * CC;
        int yi = iy0 + r;
        my[r] = (yi >= 0 && yi < HH) ? 1.f : 0.f;
        int yc = yi < 0 ? 0 : (yi > HH - 1 ? HH - 1 : yi);
        roff[r] = yc * (WW * CC);
    }
    // masks folded into bilinear weights
    float wl[5], wr_[5], vt[5], vb2[5];
#pragma unroll
    for (int i = 0; i < 5; ++i) {
        wl[i]  = (1.f - wx) * mx[i];
        wr_[i] = wx * mx[i + 1];
        vt[i]  = (1.f - wy) * my[i];
        vb2[i] = wy * my[i + 1];
    }

    const ushort16* kb = kp + (size_t)n * HWp * CC + c0;
    const ushort16* vbp = vp + (size_t)n * HWp * CC + c0;
    ushort16* qb = qoh + (size_t)pix * CC + c0;

    uint4 qraw = *reinterpret_cast<const uint4*>(qb);
    float qv[8] = { bf_lo(qraw.x), bf_hi(qraw.x), bf_lo(qraw.y), bf_hi(qraw.y),
                    bf_lo(qraw.z), bf_hi(qraw.z), bf_lo(qraw.w), bf_hi(qraw.w) };

    // ---- K pass: row-streamed patch dot + blends -> l[25] partials ----
    float l[25];
#pragma unroll
    for (int r = 0; r < 6; ++r) {
        const ushort16* krow = kb + roff[r];
        float pd[6];
#pragma unroll
        for (int rx = 0; rx < 6; ++rx) {
            uint4 u = *reinterpret_cast<const uint4*>(krow + coff[rx]);
            float s = qv[0] * bf_lo(u.x) + qv[1] * bf_hi(u.x);
            s = fmaf(qv[2], bf_lo(u.y), s);
            s = fmaf(qv[3], bf_hi(u.y), s);
            s = fmaf(qv[4], bf_lo(u.z), s);
            s = fmaf(qv[5], bf_hi(u.z), s);
            s = fmaf(qv[6], bf_lo(u.w), s);
            s = fmaf(qv[7], bf_hi(u.w), s);
            pd[rx] = s;
        }
        float hbr[5];
#pragma unroll
        for (int kx = 0; kx < 5; ++kx)
            hbr[kx] = pd[kx] * wl[kx] + pd[kx + 1] * wr_[kx];
        if (r < 5) {
#pragma unroll
            for (int kx = 0; kx < 5; ++kx) l[r * 5 + kx] = hbr[kx] * vt[r];
        }
        if (r >= 1) {
#pragma unroll
            for (int kx = 0; kx < 5; ++kx)
                l[(r - 1) * 5 + kx] = fmaf(hbr[kx], vb2[r - 1], l[(r - 1) * 5 + kx]);
        }
    }

    // ---- reduce over 4 lanes (=32 ch) of this head ----
#pragma unroll
    for (int kk = 0; kk < 25; ++kk) {
        float s = l[kk];
        s += __shfl_xor(s, 1);
        s += __shfl_xor(s, 2);
        l[kk] = s * 0.17677669529663687f;   // 1/sqrt(32)
    }

    // ---- softmax over 25 ----
    float m = l[0];
#pragma unroll
    for (int kk = 1; kk < 25; ++kk) m = fmaxf(m, l[kk]);
    float sum = 0.f;
#pragma unroll
    for (int kk = 0; kk < 25; ++kk) { l[kk] = __expf(l[kk] - m); sum += l[kk]; }
    float inv = 1.f / sum;
#pragma unroll
    for (int kk = 0; kk < 25; ++kk) l[kk] *= inv;

    // ---- attn write: lane j of head writes kk % 4 == j (static indices) ----
    {
        int head = lg >> 2, j = lg & 3;
        float* ab = attn + (((size_t)n * NHEADS + head) * K2) * HWp + yx;
#pragma unroll
        for (int kk = 0; kk < 25; ++kk)
            if ((kk & 3) == j) ab[(size_t)kk * HWp] = l[kk];
    }

    // ---- V pass: row-streamed weights + weighted patch sum ----
    float acc[8] = {0.f, 0.f, 0.f, 0.f, 0.f, 0.f, 0.f, 0.f};
    float lhp[6] = {0.f, 0.f, 0.f, 0.f, 0.f, 0.f};
#pragma unroll
    for (int ry = 0; ry < 6; ++ry) {
        float lhc[6];
        if (ry < 5) {
            lhc[0] = l[ry * 5 + 0] * (1.f - wx);
#pragma unroll
            for (int rx = 1; rx < 5; ++rx)
                lhc[rx] = l[ry * 5 + rx] * (1.f - wx) + l[ry * 5 + rx - 1] * wx;
            lhc[5] = l[ry * 5 + 4] * wx;
        } else {
#pragma unroll
            for (int rx = 0; rx < 6; ++rx) lhc[rx] = 0.f;
        }
        float wyc = (1.f - wy) * my[ry];
        float wyp = wy * my[ry];
        const ushort16* vrow = vbp + roff[ry];
#pragma unroll
        for (int rx = 0; rx < 6; ++rx) {
            float w6 = (lhc[rx] * wyc + lhp[rx] * wyp) * mx[rx];
            uint4 u = *reinterpret_cast<const uint4*>(vrow + coff[rx]);
            acc[0] = fmaf(bf_lo(u.x), w6, acc[0]);
            acc[1] = fmaf(bf_hi(u.x), w6, acc[1]);
            acc[2] = fmaf(bf_lo(u.y), w6, acc[2]);
            acc[3] = fmaf(bf_hi(u.y), w6, acc[3]);
            acc[4] = fmaf(bf_lo(u.z), w6, acc[4]);
            acc[5] = fmaf(bf_hi(u.z), w6, acc[5]);
            acc[6] = fmaf(bf_lo(u.w), w6, acc[6]);
            acc[7] = fmaf(bf_hi(u.w), w6, acc[7]);
        }
#pragma unroll
        for (int rx = 0; rx < 6; ++rx) lhp[rx] = lhc[rx];
    }

    uint4 o;
    o.x = pack2(acc[0], acc[1]);
    o.y = pack2(acc[2], acc[3]);
    o.z = pack2(acc[4], acc[5]);
    o.w = pack2(acc[6], acc[7]);
    *reinterpret_cast<uint4*>(qb) = o;     // oh, in-place over qp
}

// ---------------------------------------------------------------------------
// Kernel 3: MFMA final projection. out[o][pix] = Wfc * oh[pix][c]^T.
// ---------------------------------------------------------------------------
__global__ __launch_bounds__(256) void fc_mfma(
    const ushort16* __restrict__ oh, const ushort16* __restrict__ wfcb,
    float* __restrict__ out)
{
    int blk = blockIdx.x;
    int gp0 = blk * 64;
    int n   = gp0 >> 12;
    int yx0 = gp0 & 4095;

    int lane = threadIdx.x & 63;
    int wid  = threadIdx.x >> 6;
    int wr = wid >> 1, wc = wid & 1;
    int p16 = lane & 15, kg = lane >> 4;

    const ushort16* ohb = oh + (size_t)gp0 * CC;

    f32x4 acc[4][2] = {};

#pragma unroll
    for (int k0 = 0; k0 < 128; k0 += 32) {
        bf16x8 A[4], B[2];
#pragma unroll
        for (int ai = 0; ai < 4; ++ai) {
            int o = wr * 64 + ai * 16 + p16;
            A[ai] = *reinterpret_cast<const bf16x8*>(&wfcb[o * 128 + k0 + kg * 8]);
        }
#pragma unroll
        for (int bj = 0; bj < 2; ++bj) {
            int px = wc * 32 + bj * 16 + p16;
            B[bj] = *reinterpret_cast<const bf16x8*>(&ohb[(size_t)px * CC + k0 + kg * 8]);
        }
#pragma unroll
        for (int ai = 0; ai < 4; ++ai)
#pragma unroll
            for (int bj = 0; bj < 2; ++bj)
                acc[ai][bj] = __builtin_amdgcn_mfma_f32_16x16x32_bf16(
                    A[ai], B[bj], acc[ai][bj], 0, 0, 0);
    }

    float* ob = out + (size_t)n * CC * HWp + yx0;
#pragma unroll
    for (int ai = 0; ai < 4; ++ai) {
        int o = wr * 64 + ai * 16 + kg * 4;
#pragma unroll
        for (int bj = 0; bj < 2; ++bj) {
            int px = wc * 32 + bj * 16 + p16;
#pragma unroll
            for (int r = 0; r < 4; ++r)
                ob[(size_t)(o + r) * HWp + px] = acc[ai][bj][r];
        }
    }
}

// ---------------------------------------------------------------------------
extern "C" void kernel_launch(void* const* d_in, const int* in_sizes, int n_in,
                              void* d_out, int out_size, void* d_ws, size_t ws_size,
                              hipStream_t stream)
{
    const float* q    = (const float*)d_in[0];
    const float* k    = (const float*)d_in[1];
    const float* v    = (const float*)d_in[2];
    const float* flow = (const float*)d_in[3];
    const float* Wq   = (const float*)d_in[4];
    const float* Wk   = (const float*)d_in[5];
    const float* Wv   = (const float*)d_in[6];
    const float* Wfc  = (const float*)d_in[7];

    float* out  = (float*)d_out;                          // [N][C][H][W]
    float* attn = out + (size_t)NB * CC * HWp;            // [N][NHEADS][K2][H][W]

    ushort16* ws = (ushort16*)d_ws;
    size_t slab = (size_t)NB * HWp * CC;
    ushort16* qp  = ws;                                   // reused as oh
    ushort16* kp  = ws + slab;
    ushort16* vp  = ws + 2 * slab;
    ushort16* wbf = ws + 3 * slab;

    wconv_kernel<<<dim3(64), dim3(256), 0, stream>>>(Wq, Wk, Wv, Wfc, wbf);
    proj_mfma<<<dim3(768), dim3(256), 0, stream>>>(q, k, v, wbf, qp, kp, vp);
    attn_kernel<<<dim3(1024), dim3(256), 0, stream>>>(qp, kp, vp, flow, attn);
    fc_mfma<<<dim3(256), dim3(256), 0, stream>>>(qp, wbf + 3 * 16384, out);
}